// Round 5
// baseline (4382.154 us; speedup 1.0000x reference)
//
#include <hip/hip_runtime.h>
#include <math.h>

#define B_SZ 32
#define T_SZ 2048
#define DIN 256
#define DH 256
#define FOUR_D 1024

// 8 WGs per batch, 512 threads each; WG (b,w) owns dims [32w, 32w+32)
#define NW 8
#define DPW 32
#define COLS 128       // preact cols per WG (4 gates x 32 dims)
#define KSEG 4         // 512 threads = 128 cols x 4 K-segments
#define KLEN 64        // K elements per segment

__global__ void zero_ws(unsigned int* p, int n) {
    int i = blockIdx.x * blockDim.x + threadIdx.x;
    if (i < n) p[i] = 0u;
}

// Fused LSTM: px GEMM folded into the scan (x.W part is h-independent).
// Per thread: 64 U-weights + 64 W-weights in registers. x row staged in LDS
// (double-buffered, wave 7 prefetches row t+1 during the poll window).
// h exchange across the 8 WGs of a batch: 64-bit agent-scope atomics carrying
// (step_tag<<32 | float_bits), parity-double-buffered (proven R2 protocol).
// Cell state lives in registers for the whole T=2048 -> single launch.
__global__ __launch_bounds__(512, 2) void lstm_fused(
    const float* __restrict__ x, const float* __restrict__ W,
    const float* __restrict__ U, const float* __restrict__ bias,
    float* __restrict__ out, unsigned long long* __restrict__ hbuf)
{
    __shared__ float x_lds[2][DIN];
    __shared__ float h_lds[DH];
    __shared__ float red[KSEG][COLS + 1];

    const int wgid = blockIdx.x;
    const int b = wgid >> 3;          // batch (batch-contiguous)
    const int w = wgid & 7;           // WG-within-batch
    const int tid = threadIdx.x;
    const int c = tid & (COLS - 1);   // col within WG: 0..127
    const int seg = tid >> 7;         // 0..3
    const int kbase = seg << 6;       // 0,64,128,192
    const int gg = c >> 5, jj = c & 31;
    const int colg = (gg << 8) + (w << 5) + jj;   // global preact column

    // ---- prologue: weights to registers (one-time)
    float ureg[KLEN], wreg[KLEN];
#pragma unroll
    for (int kk = 0; kk < KLEN; ++kk) {
        ureg[kk] = U[(size_t)(kbase + kk) * FOUR_D + colg];
        wreg[kk] = W[(size_t)(kbase + kk) * FOUR_D + colg];
    }
    const float breg = bias[colg];
    float c_reg = 0.0f;               // cell state (dim-threads only use it)

    // x row 0 -> x_lds[0]
    if (tid < 64) {
        float4 v = *(const float4*)&x[((size_t)b * T_SZ + 0) * DIN + tid * 4];
        *(float4*)&x_lds[0][tid * 4] = v;
    }
    __syncthreads();

    float4 xr = make_float4(0.f, 0.f, 0.f, 0.f);   // wave-7 prefetch register

    for (int tt = 0; tt < T_SZ; ++tt) {
        // wave 7: issue global prefetch of x row tt+1 (latency hides under poll)
        if (tid >= 448 && tt + 1 < T_SZ) {
            int l = tid - 448;
            xr = *(const float4*)&x[((size_t)b * T_SZ + (tt + 1)) * DIN + l * 4];
        }

        // acquire h_tt: threads 0..255 poll their own dim (tag == tt)
        if (tid < DH) {
            if (tt == 0) {
                h_lds[tid] = 0.0f;
            } else {
                const unsigned long long want = (unsigned long long)(unsigned)tt;
                const unsigned long long* slot = hbuf +
                    (((size_t)(tt & 1) * B_SZ + b) * DH + tid);
                unsigned long long v;
                do {
                    v = __hip_atomic_load(slot, __ATOMIC_RELAXED,
                                          __HIP_MEMORY_SCOPE_AGENT);
                } while ((v >> 32) != want);
                h_lds[tid] = __uint_as_float((unsigned)v);
            }
        }
        __syncthreads();   // B1: h_lds (and x_lds slot) ready

        // fused GEMV: pre_seg = sum_k x[k]*W[k][col] + h[k]*U[k][col], k in seg
        const float* xrow = x_lds[tt & 1];
        float a0 = 0.f, a1 = 0.f, a2 = 0.f, a3 = 0.f;
#pragma unroll
        for (int i = 0; i < KLEN; i += 4) {
            float4 hv = *(const float4*)&h_lds[kbase + i];
            float4 xv = *(const float4*)&xrow[kbase + i];
            a0 += hv.x * ureg[i]     + xv.x * wreg[i];
            a1 += hv.y * ureg[i + 1] + xv.y * wreg[i + 1];
            a2 += hv.z * ureg[i + 2] + xv.z * wreg[i + 2];
            a3 += hv.w * ureg[i + 3] + xv.w * wreg[i + 3];
        }
        float pr = (a0 + a1) + (a2 + a3);
        if (seg == 0) pr += breg;
        red[seg][c] = pr;

        // wave 7: stash prefetched row into the other parity slot (pre-B2)
        if (tid >= 448 && tt + 1 < T_SZ) {
            int l = tid - 448;
            *(float4*)&x_lds[(tt + 1) & 1][l * 4] = xr;
        }
        __syncthreads();   // B2: red (and next x row) ready

        // tail: dim-threads finish gates, cell, publish, out
        if (tid < DPW) {
            float pi = red[0][tid]       + red[1][tid]
                     + red[2][tid]       + red[3][tid];
            float pf = red[0][32 + tid]  + red[1][32 + tid]
                     + red[2][32 + tid]  + red[3][32 + tid];
            float po = red[0][64 + tid]  + red[1][64 + tid]
                     + red[2][64 + tid]  + red[3][64 + tid];
            float pg = red[0][96 + tid]  + red[1][96 + tid]
                     + red[2][96 + tid]  + red[3][96 + tid];
            float ig = 1.0f / (1.0f + __expf(-pi));
            float fg = 1.0f / (1.0f + __expf(-pf));
            float og = 1.0f / (1.0f + __expf(-po));
            float eg = __expf(-2.0f * pg);
            float gv = 2.0f / (1.0f + eg) - 1.0f;
            float cn = fg * c_reg + ig * gv;
            c_reg = cn;
            float ec = __expf(-2.0f * cn);
            float hn = og * (2.0f / (1.0f + ec) - 1.0f);
            const int d = (w << 5) + tid;
            // publish FIRST (critical path), out-store after
            unsigned long long pv =
                ((unsigned long long)(unsigned)(tt + 1) << 32) |
                (unsigned long long)__float_as_uint(hn);
            __hip_atomic_store(hbuf + (((size_t)((tt + 1) & 1) * B_SZ + b) * DH + d),
                               pv, __ATOMIC_RELAXED, __HIP_MEMORY_SCOPE_AGENT);
            out[((size_t)b * T_SZ + tt) * DH + d] = hn;
        }
        // no third barrier: next red write is gated behind B1_{tt+1} rendezvous
        // (tail threads must arrive there), h_lds rewrite gated behind B2_tt.
    }
}

extern "C" void kernel_launch(void* const* d_in, const int* in_sizes, int n_in,
                              void* d_out, int out_size, void* d_ws, size_t ws_size,
                              hipStream_t stream) {
    const float* x    = (const float*)d_in[0];
    const float* W    = (const float*)d_in[1];
    const float* U    = (const float*)d_in[2];
    const float* bias = (const float*)d_in[3];
    float* out = (float*)d_out;

    // ws layout: hbuf 128KB @ 0 (tagged h, parity-double-buffered)
    unsigned long long* hbuf = (unsigned long long*)d_ws;

    // zero hbuf each launch (tags must not alias current-call step numbers)
    int zero_words = (128 * 1024) / 4;
    zero_ws<<<(zero_words + 255) / 256, 256, 0, stream>>>((unsigned int*)d_ws, zero_words);

    lstm_fused<<<B_SZ * NW, 512, 0, stream>>>(x, W, U, bias, out, hbuf);
}

// Round 6
// 4215.181 us; speedup vs baseline: 1.0396x; 1.0396x over previous
//
#include <hip/hip_runtime.h>
#include <math.h>

#define B_SZ 32
#define T_SZ 2048
#define DIN 256
#define DH 256
#define FOUR_D 1024

// 8 WGs per batch, 1024 threads each; WG (b,w) owns dims [32w, 32w+32)
#define NW 8
#define DPW 32
#define COLS 128       // preact cols per WG (4 gates x 32 dims)
#define NTHR 1024
#define KSEG 8         // 1024 threads = 128 cols x 8 K-segments
#define KLEN 32        // K elements per segment -> 32 U + 32 W regs/thread

typedef unsigned int u32x4 __attribute__((ext_vector_type(4)));

__global__ void zero_ws(unsigned int* p, int n) {
    int i = blockIdx.x * blockDim.x + threadIdx.x;
    if (i < n) p[i] = 0u;
}

// 16B poll load, L1+L2-bypassing (served at the coherent point where
// agent-scope atomic stores land). Covers 2 tagged 8B slots; each slot's
// own tag catches tearing. Fallback below keeps this assumption-free.
__device__ __forceinline__ u32x4 poll_load16(const unsigned long long* p) {
    u32x4 r;
    asm volatile("global_load_dwordx4 %0, %1, off sc0 sc1\n\t"
                 "s_waitcnt vmcnt(0)"
                 : "=v"(r) : "v"(p) : "memory");
    return r;
}

// Fused LSTM, single launch. Per thread: 32 U + 32 W weights in registers
// (block=1024 so per-thread slice is small enough to stay register-resident
// under the 128-VGPR launchability cap). x row double-buffered in LDS with
// a prefetch wave. x.W partial computed BEFORE the h-poll (h-independent).
// h exchange: 64-bit (tag<<32|bits) slots, parity double-buffered; publish
// via proven agent-scope atomic store; consume via 16B bypass loads with a
// bounded-try fallback to the proven atomic-load path (deadlock-impossible).
__global__ __launch_bounds__(NTHR) void lstm_fused2(
    const float* __restrict__ x, const float* __restrict__ W,
    const float* __restrict__ U, const float* __restrict__ bias,
    float* __restrict__ out, unsigned long long* __restrict__ hbuf)
{
    __shared__ float x_lds[2][DIN];
    __shared__ float h_lds[DH];
    __shared__ float red[KSEG][COLS + 4];

    const int b = blockIdx.x >> 3;     // batch (batch-contiguous)
    const int w = blockIdx.x & 7;      // WG-within-batch
    const int tid = threadIdx.x;
    const int c = tid & (COLS - 1);    // col within WG: 0..127
    const int seg = tid >> 7;          // 0..7
    const int kbase = seg << 5;        // 0,32,...,224
    const int gg = c >> 5, jj = c & 31;
    const int colg = (gg << 8) + (w << 5) + jj;   // global preact column

    // ---- one-time: weights to registers
    float ureg[KLEN], wreg[KLEN];
#pragma unroll
    for (int kk = 0; kk < KLEN; ++kk) {
        ureg[kk] = U[(size_t)(kbase + kk) * FOUR_D + colg];
        wreg[kk] = W[(size_t)(kbase + kk) * FOUR_D + colg];
    }
    const float breg = (seg == 0) ? bias[colg] : 0.0f;
    float c_reg = 0.0f;

    // x row 0 -> x_lds[0]
    if (tid < 64) {
        float4 v = *(const float4*)&x[((size_t)b * T_SZ) * DIN + tid * 4];
        *(float4*)&x_lds[0][tid * 4] = v;
    }
    __syncthreads();

    float4 xr = make_float4(0.f, 0.f, 0.f, 0.f);   // prefetch-wave register

    for (int tt = 0; tt < T_SZ; ++tt) {
        // prefetch wave (last 64 threads): issue global load of x row tt+1
        if (tid >= NTHR - 64 && tt + 1 < T_SZ) {
            int l = tid - (NTHR - 64);
            xr = *(const float4*)&x[((size_t)b * T_SZ + tt + 1) * DIN + l * 4];
        }

        // h-independent partial: a += x[k]*W[k][col] (off the critical path)
        const float* xrow = x_lds[tt & 1];
        float a0 = 0.f, a1 = 0.f, a2 = 0.f, a3 = 0.f;
#pragma unroll
        for (int i = 0; i < KLEN; i += 4) {
            float4 xv = *(const float4*)&xrow[kbase + i];
            a0 += xv.x * wreg[i];     a1 += xv.y * wreg[i + 1];
            a2 += xv.z * wreg[i + 2]; a3 += xv.w * wreg[i + 3];
        }

        // acquire h_tt: 128 pollers, 2 dims each via one 16B bypass load
        if (tid < 128) {
            if (tt == 0) {
                *(float2*)&h_lds[tid * 2] = make_float2(0.f, 0.f);
            } else {
                const unsigned want = (unsigned)tt;
                const unsigned long long* slot =
                    hbuf + (((size_t)(tt & 1) * B_SZ + b) * DH + tid * 2);
                int tries = 0;
                for (;;) {
                    u32x4 v = poll_load16(slot);
                    if (v[1] == want && v[3] == want) {
                        h_lds[tid * 2]     = __uint_as_float(v[0]);
                        h_lds[tid * 2 + 1] = __uint_as_float(v[2]);
                        break;
                    }
                    if (++tries > 64) {   // proven-path insurance (no hang)
                        unsigned long long q0, q1;
                        do { q0 = __hip_atomic_load(slot, __ATOMIC_RELAXED,
                                                    __HIP_MEMORY_SCOPE_AGENT);
                        } while ((unsigned)(q0 >> 32) != want);
                        do { q1 = __hip_atomic_load(slot + 1, __ATOMIC_RELAXED,
                                                    __HIP_MEMORY_SCOPE_AGENT);
                        } while ((unsigned)(q1 >> 32) != want);
                        h_lds[tid * 2]     = __uint_as_float((unsigned)q0);
                        h_lds[tid * 2 + 1] = __uint_as_float((unsigned)q1);
                        break;
                    }
                }
            }
        }
        __syncthreads();   // B1: h_lds (and x_lds slot) ready

        // critical-path GEMV: a += h[k]*U[k][col], 32 FMAs from registers
#pragma unroll
        for (int i = 0; i < KLEN; i += 4) {
            float4 hv = *(const float4*)&h_lds[kbase + i];
            a0 += hv.x * ureg[i];     a1 += hv.y * ureg[i + 1];
            a2 += hv.z * ureg[i + 2]; a3 += hv.w * ureg[i + 3];
        }
        red[seg][c] = ((a0 + a1) + (a2 + a3)) + breg;

        // prefetch wave: stash next x row into the other parity slot
        if (tid >= NTHR - 64 && tt + 1 < T_SZ) {
            int l = tid - (NTHR - 64);
            *(float4*)&x_lds[(tt + 1) & 1][l * 4] = xr;
        }
        __syncthreads();   // B2: red (and next x row) ready

        // tail: dim-threads finish gates, cell update, publish, out-store
        if (tid < DPW) {
            float pi = 0.f, pf = 0.f, po = 0.f, pg = 0.f;
#pragma unroll
            for (int s2 = 0; s2 < KSEG; ++s2) {
                pi += red[s2][tid];
                pf += red[s2][32 + tid];
                po += red[s2][64 + tid];
                pg += red[s2][96 + tid];
            }
            float ig = 1.0f / (1.0f + __expf(-pi));
            float fg = 1.0f / (1.0f + __expf(-pf));
            float og = 1.0f / (1.0f + __expf(-po));
            float eg = __expf(-2.0f * pg);
            float gv = 2.0f / (1.0f + eg) - 1.0f;
            float cn = fg * c_reg + ig * gv;
            c_reg = cn;
            float ec = __expf(-2.0f * cn);
            float hn = og * (2.0f / (1.0f + ec) - 1.0f);
            const int d = (w << 5) + tid;
            // publish FIRST (critical path), out-store after
            unsigned long long pv =
                ((unsigned long long)(unsigned)(tt + 1) << 32) |
                (unsigned long long)__float_as_uint(hn);
            __hip_atomic_store(hbuf + (((size_t)((tt + 1) & 1) * B_SZ + b) * DH + d),
                               pv, __ATOMIC_RELAXED, __HIP_MEMORY_SCOPE_AGENT);
            out[((size_t)b * T_SZ + tt) * DH + d] = hn;
        }
        // no third barrier: next-iter red writes are gated behind B1_{tt+1}
        // (tail threads must arrive there), h_lds rewrite gated behind B2_tt.
    }
}

extern "C" void kernel_launch(void* const* d_in, const int* in_sizes, int n_in,
                              void* d_out, int out_size, void* d_ws, size_t ws_size,
                              hipStream_t stream) {
    const float* x    = (const float*)d_in[0];
    const float* W    = (const float*)d_in[1];
    const float* U    = (const float*)d_in[2];
    const float* bias = (const float*)d_in[3];
    float* out = (float*)d_out;

    // ws layout: hbuf 128KB @ 0 (tagged h, parity-double-buffered)
    unsigned long long* hbuf = (unsigned long long*)d_ws;

    // zero hbuf each launch (tags must not alias current-call step numbers,
    // and we must not rely on state left by previous calls)
    int zero_words = (128 * 1024) / 4;
    zero_ws<<<(zero_words + 255) / 256, 256, 0, stream>>>((unsigned int*)d_ws, zero_words);

    lstm_fused2<<<B_SZ * NW, NTHR, 0, stream>>>(x, W, U, bias, out, hbuf);
}